// Round 1
// baseline (197.542 us; speedup 1.0000x reference)
//
#include <hip/hip_runtime.h>
#include <math.h>

#define N_NODES 50000
#define N_EDGES 800000
#define IN_FEAT 256
#define DIM_H   64
#define NPAD    50176   // padded N slots; 50176 = 392 * 128
#define CAP     48      // per-node capacity; Poisson(16) max deg ~40 << 48
#define NBUK    392     // dst buckets (128 nodes each)
#define BNODES  128
#define BCAP    3072    // bucket capacity; mean 2041, >20 sigma headroom
#define EPB     4096    // edges per binA block
#define PBLKS   391     // proj blocks  = ceil(N/128)
#define ABLKS   196     // binA blocks  = ceil(E/EPB)
#define SPLIT   8       // gather blocks per bucket (occupancy: 12.3 blk/CU grid)
#define PNODES  16      // nodes per gather block (BNODES/SPLIT)

typedef __attribute__((ext_vector_type(8)))  short  s16x8;   // 8 bf16 (4 VGPRs)
typedef __attribute__((ext_vector_type(16))) float  f32x16;  // MFMA 32x32 acc

__device__ __forceinline__ float bcast_f(float v, int k) {
  return __int_as_float(__builtin_amdgcn_readlane(__float_as_int(v), k));
}
__device__ __forceinline__ short f2bf(float f) {   // RNE f32->bf16
  unsigned u = __float_as_uint(f);
  u += 0x7fffu + ((u >> 16) & 1u);
  return (short)(u >> 16);
}

// ---------------------------------------------------------------------------
// proj_binA: one kernel, two independent block roles (they overlap on-chip;
// binA is VMEM/atomic-bound and hides under proj blocks).
//  blocks [0,PBLKS):    proj — h = x @ W_src (mfma_f32_32x32x16_bf16), h
//                       stored pair-packed bf16 (128 B/row); a_src from f32
//                       accumulators; a_dst = x @ (W_dst@att_dst) pre-cvt f32.
//                       MLP fix (this round): all 32 x-loads issued before the
//                       MFMA loop; B-frags read from LDS per iteration (frees
//                       the 128-VGPR bfr preload so x data can hold registers).
//  blocks [PBLKS,+ABLKS): binA — partition edges into 392 dst-buckets with
//                       LDS histogram + one global atomic per (block,bucket),
//                       grouped writes. Record: src:16 | dstLocal:16.
// ---------------------------------------------------------------------------
__global__ __launch_bounds__(256) void proj_binA_kernel(
    const float* __restrict__ x,
    const float* __restrict__ Wsrc,
    const float* __restrict__ Wdst,
    const float* __restrict__ att_src,
    const float* __restrict__ att_dst,
    const int* __restrict__ ei,
    unsigned* __restrict__ hbf,
    float* __restrict__ a_src,
    float* __restrict__ a_dst,
    int* __restrict__ gbc,
    unsigned* __restrict__ binbuf) {
  __shared__ short wfrag[16 * 2 * 64 * 8];   // proj: B-frags (32 KB); binA: hist
  __shared__ float wdl[IN_FEAT];             // W_dst @ att_dst
  __shared__ float attl[DIM_H];

  const int tid = threadIdx.x;

  // ---------------- binA role ----------------
  if (blockIdx.x >= PBLKS) {
    int* bcnt = (int*)wfrag;          // overlay: NBUK ints
    int* wcur = bcnt + NBUK;          // overlay: NBUK ints
    const int e0 = (blockIdx.x - PBLKS) * EPB;

    for (int b = tid; b < NBUK; b += 256) bcnt[b] = 0;
    __syncthreads();

    int dst[16];
    #pragma unroll
    for (int i = 0; i < 16; ++i) {
      int e = e0 + tid + 256 * i;
      dst[i] = (e < N_EDGES) ? ei[N_EDGES + e] : -1;
      if (dst[i] >= 0) atomicAdd(&bcnt[dst[i] >> 7], 1);
    }
    __syncthreads();

    for (int b = tid; b < NBUK; b += 256) {
      int c = bcnt[b];
      wcur[b] = c ? atomicAdd(&gbc[b], c) : 0;
    }
    __syncthreads();

    #pragma unroll
    for (int i = 0; i < 16; ++i) {
      int e = e0 + tid + 256 * i;
      if (e < N_EDGES) {
        int s = ei[e];
        int b = dst[i] >> 7;
        int pos = atomicAdd(&wcur[b], 1);
        if (pos < BCAP)
          binbuf[(long)b * BCAP + pos] =
              (unsigned)s | ((unsigned)(dst[i] & 127) << 16);
      }
    }
    return;
  }

  // ---------------- proj role ----------------
  const int lane = tid & 63;
  const int wv   = tid >> 6;

  if (tid < DIM_H) attl[tid] = att_dst[tid];
  __syncthreads();

  {
    float s = 0.f;
    const float4* row = (const float4*)(Wdst + (long)tid * DIM_H);
    #pragma unroll
    for (int q = 0; q < 16; ++q) {
      float4 r = row[q];
      s = fmaf(r.x, attl[4 * q + 0], s);
      s = fmaf(r.y, attl[4 * q + 1], s);
      s = fmaf(r.z, attl[4 * q + 2], s);
      s = fmaf(r.w, attl[4 * q + 3], s);
    }
    wdl[tid] = s;
  }

  // stage W_src into B-frag order: lane l of frag (s,t) holds
  // W[k = s*16 + (l>>5)*8 + j][n = (l&31) + 32*t], j contiguous.
  for (int e = tid; e < IN_FEAT * DIM_H; e += 256) {
    int k = e >> 6, n = e & 63;
    int s = k >> 4, half = (k >> 3) & 1, j = k & 7, t = n >> 5;
    int fl = (n & 31) + 32 * half;
    wfrag[((s * 2 + t) * 64 + fl) * 8 + j] = f2bf(Wsrc[e]);
  }
  __syncthreads();

  const int base = (blockIdx.x * 4 + wv) * 32;
  int row = base + (lane & 31); if (row > N_NODES - 1) row = N_NODES - 1;
  const int koff = (lane >> 5) * 8;
  const float* px = x + (long)row * IN_FEAT + koff;

  // issue ALL x loads first: 32 outstanding dwordx4 per wave (MLP >> the
  // previous ~8; this is what 60us->~30us rides on)
  float4 va[16], vb[16];
  #pragma unroll
  for (int s = 0; s < 16; ++s) {
    va[s] = *(const float4*)(px + s * 16);
    vb[s] = *(const float4*)(px + s * 16 + 4);
  }

  f32x16 acc0, acc1;
  #pragma unroll
  for (int i = 0; i < 16; ++i) { acc0[i] = 0.f; acc1[i] = 0.f; }
  float pd = 0.f;

  #pragma unroll
  for (int s = 0; s < 16; ++s) {
    float4 w1 = *(const float4*)(wdl + s * 16 + koff);
    float4 w2 = *(const float4*)(wdl + s * 16 + koff + 4);
    pd = fmaf(va[s].x, w1.x, pd); pd = fmaf(va[s].y, w1.y, pd);
    pd = fmaf(va[s].z, w1.z, pd); pd = fmaf(va[s].w, w1.w, pd);
    pd = fmaf(vb[s].x, w2.x, pd); pd = fmaf(vb[s].y, w2.y, pd);
    pd = fmaf(vb[s].z, w2.z, pd); pd = fmaf(vb[s].w, w2.w, pd);
    s16x8 a;
    a[0] = f2bf(va[s].x); a[1] = f2bf(va[s].y);
    a[2] = f2bf(va[s].z); a[3] = f2bf(va[s].w);
    a[4] = f2bf(vb[s].x); a[5] = f2bf(vb[s].y);
    a[6] = f2bf(vb[s].z); a[7] = f2bf(vb[s].w);
    s16x8 b0 = *(const s16x8*)(wfrag + ((s * 2 + 0) * 64 + lane) * 8);
    s16x8 b1 = *(const s16x8*)(wfrag + ((s * 2 + 1) * 64 + lane) * 8);
    acc0 = __builtin_amdgcn_mfma_f32_32x32x16_bf16(a, b0, acc0, 0, 0, 0);
    acc1 = __builtin_amdgcn_mfma_f32_32x32x16_bf16(a, b1, acc1, 0, 0, 0);
  }

  const int col = lane & 31;
  const int rhi = 4 * (lane >> 5);

  #pragma unroll
  for (int r = 0; r < 16; ++r) {
    int node = base + (r & 3) + 8 * (r >> 2) + rhi;
    if (node < N_NODES) {
      unsigned p = (unsigned)(unsigned short)f2bf(acc0[r]) |
                   ((unsigned)(unsigned short)f2bf(acc1[r]) << 16);
      hbf[(long)node * 32 + col] = p;
    }
  }

  float att0 = att_src[col];
  float att1 = att_src[col + 32];
  #pragma unroll
  for (int r = 0; r < 16; ++r) {
    float t = acc0[r] * att0 + acc1[r] * att1;
    t += __shfl_xor(t, 1, 64);
    t += __shfl_xor(t, 2, 64);
    t += __shfl_xor(t, 4, 64);
    t += __shfl_xor(t, 8, 64);
    t += __shfl_xor(t, 16, 64);
    int node = base + (r & 3) + 8 * (r >> 2) + rhi;
    if (col == 0 && node < N_NODES) a_src[node] = t;
  }

  float pds = pd + __shfl_xor(pd, 32, 64);
  int node = base + (lane & 31);
  if (lane < 32 && node < N_NODES) a_dst[node] = pds;
}

// ---------------------------------------------------------------------------
// gatherfused: block = 1/8 bucket (16 nodes). Phase 1: scan the bucket's binA
// records (coalesced), keep own nodes' edges, w = exp(leaky(a_s+a_d)), bin
// into LDS CSR (3 KB). Phase 2: wave per 4 nodes; 8-lane edge groups, edge
// loop unrolled x2 (16 edges / 2 KB in flight); one dwordx4 = one pair-packed
// bf16 h row (128 B). Epilogue: normalize + bias + relu + W_lin (LDS, 4-way
// split accumulator chain) + store.
// LDS ~19.4 KB -> 8 blocks/CU; grid 3136 = 12.3 blocks/CU -> occupancy-rich.
// ---------------------------------------------------------------------------
__global__ __launch_bounds__(256) void gatherfused_kernel(
    const unsigned* __restrict__ binbuf,
    const int* __restrict__ gbc,
    const float* __restrict__ a_src,
    const float* __restrict__ a_dst,
    const unsigned* __restrict__ hbf,
    const float* __restrict__ bias_conv,
    const float* __restrict__ W_lin,
    const float* __restrict__ b_lin,
    float* __restrict__ out) {
  __shared__ unsigned rec[PNODES * CAP];   // {bf16(w):16 | src:16}, 3 KB
  __shared__ int   lcnt[PNODES];
  __shared__ float adl[PNODES];
  __shared__ float wl[64 * 64];            // W_lin[k][j], 16 KB

  const int tid    = threadIdx.x;
  const int bucket = blockIdx.x >> 3;      // SPLIT = 8
  const int part   = blockIdx.x & 7;
  const int nb     = bucket * BNODES + part * PNODES;  // first node
  const int dlo    = part * PNODES;

  for (int i = tid; i < 4096; i += 256) wl[i] = W_lin[i];
  if (tid < PNODES) {
    lcnt[tid] = 0;
    adl[tid]  = a_dst[nb + tid];   // nodes >= N_NODES never referenced
  }
  __syncthreads();

  // phase 1: bin my nodes' edges into LDS
  int count = gbc[bucket]; if (count > BCAP) count = BCAP;
  const unsigned* bb = binbuf + (long)bucket * BCAP;
  for (int i = tid; i < count; i += 256) {
    unsigned u = bb[i];
    int dl = (int)(u >> 16) - dlo;
    if ((unsigned)dl < PNODES) {
      int s = (int)(u & 0xffffu);
      float sc = a_src[s] + adl[dl];
      sc = sc >= 0.f ? sc : 0.2f * sc;      // leaky_relu 0.2
      float w = __expf(sc);
      int pos = atomicAdd(&lcnt[dl], 1);
      if (pos < CAP)                        // never fires (maxdeg << CAP)
        rec[dl * CAP + pos] =
            ((unsigned)(unsigned short)f2bf(w) << 16) | (u & 0xffffu);
    }
  }
  __syncthreads();

  // phase 2: gather + epilogue
  const int lane = tid & 63;
  const int wv   = __builtin_amdgcn_readfirstlane(tid >> 6);
  const int grp8 = lane >> 3;
  const int ql8  = lane & 7;
  const float bj  = bias_conv[lane];
  const float blj = b_lin[lane];

  for (int q = 0; q < 4; ++q) {
    const int dl = wv * 4 + q;
    const int n  = nb + dl;
    int m = lcnt[dl]; if (m > CAP) m = CAP;

    float alo[4] = {0.f, 0.f, 0.f, 0.f};
    float ahi[4] = {0.f, 0.f, 0.f, 0.f};
    float den = 0.f;

    for (int j = 0; j < m; j += 16) {
      int idx0 = j + grp8;
      int idx1 = j + 8 + grp8;
      int ci0 = idx0 < m ? idx0 : m - 1;    // m >= 1 inside the loop
      int ci1 = idx1 < m ? idx1 : m - 1;
      unsigned u0 = rec[dl * CAP + ci0];    // LDS broadcast within group
      unsigned u1 = rec[dl * CAP + ci1];
      float w0 = __uint_as_float(u0 & 0xffff0000u);
      float w1 = __uint_as_float(u1 & 0xffff0000u);
      if (idx0 >= m) w0 = 0.f;
      if (idx1 >= m) w1 = 0.f;
      int s0 = (int)(u0 & 0xffffu);
      int s1 = (int)(u1 & 0xffffu);
      uint4 hp0 = *(const uint4*)(hbf + (long)s0 * 32 + ql8 * 4);
      uint4 hp1 = *(const uint4*)(hbf + (long)s1 * 32 + ql8 * 4);
      alo[0] = fmaf(w0, __uint_as_float(hp0.x << 16),         alo[0]);
      ahi[0] = fmaf(w0, __uint_as_float(hp0.x & 0xffff0000u), ahi[0]);
      alo[1] = fmaf(w0, __uint_as_float(hp0.y << 16),         alo[1]);
      ahi[1] = fmaf(w0, __uint_as_float(hp0.y & 0xffff0000u), ahi[1]);
      alo[2] = fmaf(w0, __uint_as_float(hp0.z << 16),         alo[2]);
      ahi[2] = fmaf(w0, __uint_as_float(hp0.z & 0xffff0000u), ahi[2]);
      alo[3] = fmaf(w0, __uint_as_float(hp0.w << 16),         alo[3]);
      ahi[3] = fmaf(w0, __uint_as_float(hp0.w & 0xffff0000u), ahi[3]);
      den += w0;
      alo[0] = fmaf(w1, __uint_as_float(hp1.x << 16),         alo[0]);
      ahi[0] = fmaf(w1, __uint_as_float(hp1.x & 0xffff0000u), ahi[0]);
      alo[1] = fmaf(w1, __uint_as_float(hp1.y << 16),         alo[1]);
      ahi[1] = fmaf(w1, __uint_as_float(hp1.y & 0xffff0000u), ahi[1]);
      alo[2] = fmaf(w1, __uint_as_float(hp1.z << 16),         alo[2]);
      ahi[2] = fmaf(w1, __uint_as_float(hp1.z & 0xffff0000u), ahi[2]);
      alo[3] = fmaf(w1, __uint_as_float(hp1.w << 16),         alo[3]);
      ahi[3] = fmaf(w1, __uint_as_float(hp1.w & 0xffff0000u), ahi[3]);
      den += w1;
    }

    // combine the 8 groups (lanes sharing lane&7 hold the same dims)
    #pragma unroll
    for (int mm = 8; mm <= 32; mm <<= 1) {
      #pragma unroll
      for (int c = 0; c < 4; ++c) {
        alo[c] += __shfl_xor(alo[c], mm, 64);
        ahi[c] += __shfl_xor(ahi[c], mm, 64);
      }
      den += __shfl_xor(den, mm, 64);
    }
    // transpose to lane=dim
    int srcl = (lane & 31) >> 2;
    float v0 = __shfl(alo[0], srcl, 64);
    float v1 = __shfl(alo[1], srcl, 64);
    float v2 = __shfl(alo[2], srcl, 64);
    float v3 = __shfl(alo[3], srcl, 64);
    float v4 = __shfl(ahi[0], srcl, 64);
    float v5 = __shfl(ahi[1], srcl, 64);
    float v6 = __shfl(ahi[2], srcl, 64);
    float v7 = __shfl(ahi[3], srcl, 64);
    int c4 = lane & 3;
    float losel = (c4 == 0) ? v0 : (c4 == 1) ? v1 : (c4 == 2) ? v2 : v3;
    float hisel = (c4 == 0) ? v4 : (c4 == 1) ? v5 : (c4 == 2) ? v6 : v7;
    float accl = (lane >> 5) ? hisel : losel;

    float inv = den > 0.f ? 1.0f / den : 0.f;  // empty segment -> bias only
    float z = fmaf(accl, inv, bj);
    float h = fmaxf(z, 0.f);
    // 4-way split accumulator chain (was a 64-deep serial fma chain)
    float o0 = blj, o1 = 0.f, o2 = 0.f, o3 = 0.f;
    #pragma unroll
    for (int k = 0; k < 64; k += 4) {
      o0 = fmaf(bcast_f(h, k + 0), wl[(k + 0) * 64 + lane], o0);
      o1 = fmaf(bcast_f(h, k + 1), wl[(k + 1) * 64 + lane], o1);
      o2 = fmaf(bcast_f(h, k + 2), wl[(k + 2) * 64 + lane], o2);
      o3 = fmaf(bcast_f(h, k + 3), wl[(k + 3) * 64 + lane], o3);
    }
    float o = (o0 + o1) + (o2 + o3);
    if (n < N_NODES) out[(long)n * DIM_H + lane] = o;
  }
}

// ---------------------------------------------------------------------------
// Workspace need: hbf 6.4 MB + a_src/a_dst 0.4 MB + gbc 2 KB + binbuf 4.8 MB
// ~= 11.6 MB — well under the provided ws.
// ---------------------------------------------------------------------------
extern "C" void kernel_launch(void* const* d_in, const int* in_sizes, int n_in,
                              void* d_out, int out_size, void* d_ws, size_t ws_size,
                              hipStream_t stream) {
  const float* x        = (const float*)d_in[0];
  const int*   ei       = (const int*)d_in[1];
  const float* Wsrc     = (const float*)d_in[2];
  const float* Wdst     = (const float*)d_in[3];
  const float* att_src  = (const float*)d_in[4];
  const float* att_dst  = (const float*)d_in[5];
  const float* bias_cv  = (const float*)d_in[6];
  const float* W_lin    = (const float*)d_in[7];
  const float* b_lin    = (const float*)d_in[8];
  float* out = (float*)d_out;

  unsigned* hbf    = (unsigned*)d_ws;          // N*32 u32 (6.4 MB)
  float*    a_src  = (float*)(hbf + 1600000);  // NPAD f32
  float*    a_dst  = a_src + NPAD;             // NPAD f32
  int*      gbc    = (int*)(a_dst + NPAD);     // 512 i32 bucket cursors
  unsigned* binbuf = (unsigned*)(gbc + 512);   // NBUK*BCAP u32 (4.8 MB)

  hipMemsetAsync(gbc, 0, 512 * sizeof(int), stream);

  proj_binA_kernel<<<PBLKS + ABLKS, 256, 0, stream>>>(
      x, Wsrc, Wdst, att_src, att_dst, ei, hbf, a_src, a_dst, gbc, binbuf);

  gatherfused_kernel<<<NBUK * SPLIT, 256, 0, stream>>>(
      binbuf, gbc, a_src, a_dst, hbf, bias_cv, W_lin, b_lin, out);
}